// Round 14
// baseline (3102.232 us; speedup 1.0000x reference)
//
#include <hip/hip_runtime.h>
#include <hip/hip_bf16.h>

typedef __attribute__((ext_vector_type(8))) short s8v;
typedef __attribute__((ext_vector_type(4))) short s4v;
typedef __attribute__((ext_vector_type(4))) float f4v;

#define B_   32
#define S_   256
#define H_   300
#define HP   320
#define NW   19
#define TAGS 9

// workspace layout
#define HB_OFF    0                      // bf16 h ping-pong: 2dir*2slot*32*320*2 = 81920 B
#define LG_OFF    163840                 // fp32 logits acc: 256*32*9*4 = 294912 B
#define EM_OFF    458752                 // fp32 emissions: 256*32*9*4 = 294912 B
#define EMTAG_OFF 753664                 // fp32: 256*32*4 = 32768 B
#define ARR_OFF   786432                 // int arrive flags: 2*(S_+1)*4 = 2056 B

#define LOSS_IDX  ((long)B_*S_*TAGS)     // float element 73728

__device__ __forceinline__ short f2b(float f) {
  unsigned int u = __builtin_bit_cast(unsigned int, f);
  u = (u + 0x7FFFu + ((u >> 16) & 1u)) >> 16;      // RNE fp32 -> bf16
  return (short)u;
}
__device__ __forceinline__ float sigf(float x) { return 1.f / (1.f + __expf(-x)); }
__device__ __forceinline__ float tanh_f(float x) {
  x = fminf(fmaxf(x, -15.f), 15.f);
  float e = __expf(-2.f * x);
  return (1.f - e) / (1.f + e);
}

// ---- init: zero h ping-pong + arrive flags, init logits accumulator with lin_b ----
__global__ void k_init(const float* __restrict__ lin_b, char* __restrict__ ws) {
  short* hb = (short*)(ws + HB_OFF);
  float* lg = (float*)(ws + LG_OFF);
  int* arr  = (int*)(ws + ARR_OFF);
  long u = (long)blockIdx.x * blockDim.x + threadIdx.x;
  const long N1 = 2L * 2 * B_ * HP / 4;            // s4v units of hb (10240)
  if (u < N1) {
    s4v z; z[0]=0; z[1]=0; z[2]=0; z[3]=0;
    *(s4v*)(hb + u * 4) = z;
    return;
  }
  u -= N1;
  const long N2 = (long)S_ * B_ * TAGS;            // lg init (73728)
  if (u < N2) {
    lg[u] = lin_b[(int)(u % TAGS)];
    return;
  }
  u -= N2;
  if (u < 2*(S_+1)) arr[u] = 0;
}

// ---- persistent BiLSTM recurrence: ONE launch, 38 co-resident blocks ----
// h handoff via device-coherent (agent-scope) atomic dwords: no threadfence, no
// L2-writeback round trip; readers bypass the (non-coherent, per-XCD) L2.
__launch_bounds__(256, 1)
__global__ void k_lstm(const int* __restrict__ x, const float* __restrict__ emb,
                       const float* __restrict__ wihf, const float* __restrict__ whhf,
                       const float* __restrict__ bihf, const float* __restrict__ bhhf,
                       const float* __restrict__ wihb, const float* __restrict__ whhb,
                       const float* __restrict__ bihb, const float* __restrict__ bhhb,
                       const float* __restrict__ lin_w,
                       char* __restrict__ ws) {
  const int dir  = blockIdx.x / NW;
  const int wg   = blockIdx.x % NW;
  const int h0   = wg * 16;
  const int tid  = threadIdx.x;
  const int w    = tid >> 6;
  const int lane = tid & 63;
  const int mhat = w & 1;
  const int khalf= w >> 1;
  const int nl   = lane & 15;
  const int quad = lane >> 4;
  const int hg   = h0 + nl;                 // 0..303
  const bool hvalid = hg < H_;

  const float* Wih = dir ? wihb : wihf;
  const float* Whh = dir ? whhb : whhf;
  const float* Bih = dir ? bihb : bihf;
  const float* Bhh = dir ? bhhb : bhhf;

  short* hb = (short*)(ws + HB_OFF);
  float* lg = (float*)(ws + LG_OFF);
  int* arr  = (int*)(ws + ARR_OFF) + dir * (S_+1);

  __shared__ int   sh_idx[32];
  __shared__ short sh_x[B_*328];
  __shared__ short sh_h[B_*328];            // dword-aliased for atomic staging
  __shared__ float red[2*4*64*4];
  __shared__ float shl[B_*17];              // fp32 h of this WG's 16 dims
  __shared__ float lwl[TAGS*16];            // lin_w tile for this WG

  // ---- one-time: build weight B-fragments from fp32 into registers ----
  s8v wf[2][4][5];
  #pragma unroll
  for (int mat = 0; mat < 2; ++mat) {
    const float* W = mat ? Whh : Wih;
    #pragma unroll
    for (int nt = 0; nt < 4; ++nt) {
      const long rowbase = (long)(nt * H_ + hg) * H_;
      #pragma unroll
      for (int kci = 0; kci < 5; ++kci) {
        int kb = (khalf*5 + kci)*32 + quad*8;
        s8v v; v[0]=0;v[1]=0;v[2]=0;v[3]=0;v[4]=0;v[5]=0;v[6]=0;v[7]=0;
        if (hvalid) {
          #pragma unroll
          for (int half = 0; half < 2; ++half) {
            int k0 = kb + half*4;
            if (k0 + 4 <= H_) {
              f4v q = *(const f4v*)(W + rowbase + k0);    // 16B aligned
              v[half*4+0] = f2b(q[0]);
              v[half*4+1] = f2b(q[1]);
              v[half*4+2] = f2b(q[2]);
              v[half*4+3] = f2b(q[3]);
            } else {
              #pragma unroll
              for (int j = 0; j < 4; ++j) {
                int k = k0 + j;
                if (k < H_) v[half*4+j] = f2b(W[rowbase + k]);
              }
            }
          }
        }
        wf[mat][nt][kci] = v;
      }
    }
  }

  float bias[4];
  #pragma unroll
  for (int nt = 0; nt < 4; ++nt)
    bias[nt] = hvalid ? (Bih[nt*H_ + hg] + Bhh[nt*H_ + hg]) : 0.f;

  if (tid < TAGS*16) {
    int tg = tid / 16, n = tid % 16, hh = h0 + n;
    lwl[tid] = (hh < H_) ? lin_w[tg*(2*H_) + dir*H_ + hh] : 0.f;
  }

  float creg[4] = {0.f, 0.f, 0.f, 0.f};     // c-state lives in registers
  const int arow = (mhat*16 + nl) * 328 + quad * 8;

  for (int s = 0; s < S_; ++s) {
    const int t = dir ? (S_ - 1 - s) : s;

    if (tid < 32) sh_idx[tid] = x[tid*S_ + t];
    __syncthreads();                               // sh_idx ready; prev-iter LDS retired

    // stage x(t): fp32 emb rows -> bf16 LDS (zero-pad K to 320) — before the wait
    #pragma unroll
    for (int i = 0; i < 5; ++i) {
      int u = tid + i*256;
      int b = u / 40, kg = u % 40;
      int k0 = kg * 8;
      const float* rp = emb + (long)sh_idx[b] * H_;
      s8v v; v[0]=0;v[1]=0;v[2]=0;v[3]=0;v[4]=0;v[5]=0;v[6]=0;v[7]=0;
      if (k0 + 8 <= H_) {
        f4v a = *(const f4v*)(rp + k0);
        f4v c = *(const f4v*)(rp + k0 + 4);
        v[0]=f2b(a[0]); v[1]=f2b(a[1]); v[2]=f2b(a[2]); v[3]=f2b(a[3]);
        v[4]=f2b(c[0]); v[5]=f2b(c[1]); v[6]=f2b(c[2]); v[7]=f2b(c[3]);
      } else if (k0 < H_) {
        f4v a = *(const f4v*)(rp + k0);            // k0=296: loads 296..299
        v[0]=f2b(a[0]); v[1]=f2b(a[1]); v[2]=f2b(a[2]); v[3]=f2b(a[3]);
      }
      *(s8v*)&sh_x[b*328 + k0] = v;
    }
    __syncthreads();                               // sync1: sh_x ready

    f4v acc[4];
    #pragma unroll
    for (int nt = 0; nt < 4; ++nt) { acc[nt][0]=0.f; acc[nt][1]=0.f; acc[nt][2]=0.f; acc[nt][3]=0.f; }

    // x-GEMM first: overlaps with waiting for peers' h(s)
    #pragma unroll
    for (int kci = 0; kci < 5; ++kci) {
      s8v a = *(const s8v*)&sh_x[arow + (khalf*5 + kci)*32];
      #pragma unroll
      for (int nt = 0; nt < 4; ++nt)
        acc[nt] = __builtin_amdgcn_mfma_f32_16x16x32_bf16(a, wf[0][nt][kci], acc[nt], 0, 0, 0);
    }

    // wait for all WGs' h(s)
    if (s > 0 && tid == 0) {
      while (__hip_atomic_load(&arr[s], __ATOMIC_ACQUIRE, __HIP_MEMORY_SCOPE_AGENT) < NW)
        __builtin_amdgcn_s_sleep(1);
    }
    __syncthreads();                               // sync2

    // stage h(s): agent-scope atomic dword loads (coherent point, L2-safe)
    {
      const unsigned int* hsrc = (const unsigned int*)(hb + (long)(dir*2 + (s & 1)) * B_ * HP);
      unsigned int* shh_i = (unsigned int*)sh_h;
      #pragma unroll
      for (int i = 0; i < 20; ++i) {
        int u = tid + i*256;                       // 0..5119 dwords (32 rows x 160)
        int b = u / 160, kg = u % 160;
        shh_i[b*164 + kg] =
          __hip_atomic_load(&hsrc[b*160 + kg], __ATOMIC_RELAXED, __HIP_MEMORY_SCOPE_AGENT);
      }
    }
    __syncthreads();                               // sync3

    #pragma unroll
    for (int kci = 0; kci < 5; ++kci) {
      s8v a = *(const s8v*)&sh_h[arow + (khalf*5 + kci)*32];
      #pragma unroll
      for (int nt = 0; nt < 4; ++nt)
        acc[nt] = __builtin_amdgcn_mfma_f32_16x16x32_bf16(a, wf[1][nt][kci], acc[nt], 0, 0, 0);
    }

    // K-half reduction
    if (khalf == 1) {
      #pragma unroll
      for (int nt = 0; nt < 4; ++nt)
        *(f4v*)&red[((mhat*4 + nt)*64 + lane)*4] = acc[nt];
    }
    __syncthreads();                               // sync4

    if (khalf == 0) {
      #pragma unroll
      for (int nt = 0; nt < 4; ++nt) {
        f4v o = *(const f4v*)&red[((mhat*4 + nt)*64 + lane)*4];
        acc[nt][0]+=o[0]; acc[nt][1]+=o[1]; acc[nt][2]+=o[2]; acc[nt][3]+=o[3];
      }
      #pragma unroll
      for (int r = 0; r < 4; ++r) {
        int b = mhat*16 + quad*4 + r;
        float gi = acc[0][r] + bias[0];
        float gf = acc[1][r] + bias[1];
        float gg = acc[2][r] + bias[2];
        float go = acc[3][r] + bias[3];
        float c  = sigf(gf) * creg[r] + sigf(gi) * tanh_f(gg);
        float h  = sigf(go) * tanh_f(c);
        creg[r] = c;
        shl[b*17 + nl] = h;                        // LDS only; publish below
      }
    }
    __syncthreads();                               // sync5: shl ready

    // publish h(s+1): pack 2 bf16/dword, agent-scope atomic stores (all 256 thr)
    {
      int b = tid >> 3, j = tid & 7;               // 32 rows x 8 dword-cols
      float fa = shl[b*17 + 2*j];
      float fb = shl[b*17 + 2*j + 1];
      unsigned int pack = (unsigned int)(unsigned short)f2b(fa) |
                          ((unsigned int)(unsigned short)f2b(fb) << 16);
      unsigned int* dsti = (unsigned int*)(hb + (long)(dir*2 + ((s+1) & 1)) * B_ * HP);
      __hip_atomic_store(&dsti[b*160 + (h0 >> 1) + j], pack,
                         __ATOMIC_RELAXED, __HIP_MEMORY_SCOPE_AGENT);
    }
    __syncthreads();                               // sync6: vmcnt drained -> stores visible
    if (s + 1 < S_ && tid == 0)
      __hip_atomic_fetch_add(&arr[s+1], 1, __ATOMIC_RELEASE, __HIP_MEMORY_SCOPE_AGENT);

    // logits partial for position t (off critical path, after release)
    if (tid < B_*TAGS) {
      int b = tid / TAGS, tg = tid % TAGS;
      float sum = 0.f;
      #pragma unroll
      for (int n = 0; n < 16; ++n) sum += shl[b*17 + n] * lwl[tg*16 + n];
      atomicAdd(&lg[((long)t*B_ + b)*TAGS + tg], sum);
    }
  }
}

// ---- emit: softmax(lg) -> probs (out, FP32) + emissions/emtag (ws, fp32) ----
__global__ void k_emit(const int* __restrict__ y, char* __restrict__ ws,
                       float* __restrict__ out) {
  const float* lg = (const float*)(ws + LG_OFF);
  float* em    = (float*)(ws + EM_OFF);
  float* emtag = (float*)(ws + EMTAG_OFF);
  int g = blockIdx.x * blockDim.x + threadIdx.x;   // 8192
  int b = g & 31, t = g >> 5;

  float l[TAGS];
  #pragma unroll
  for (int tg = 0; tg < TAGS; ++tg) l[tg] = lg[((long)t*B_ + b)*TAGS + tg];
  float m = l[0];
  #pragma unroll
  for (int tg = 1; tg < TAGS; ++tg) m = fmaxf(m, l[tg]);
  float p[TAGS]; float sum = 0.f;
  #pragma unroll
  for (int tg = 0; tg < TAGS; ++tg) { p[tg] = __expf(l[tg] - m); sum += p[tg]; }
  float inv = 1.f / sum;

  int yy = y[b*S_ + t];
  int sel = (yy != -1) ? yy : 0;
  float et = 0.f;
  #pragma unroll
  for (int tg = 0; tg < TAGS; ++tg) {
    float pv = p[tg] * inv;
    out[((long)b*S_ + t)*TAGS + tg] = pv;          // FP32 output
    em[((long)t*B_ + b)*TAGS + tg] = pv;
    if (tg == sel) et = pv;
  }
  emtag[t*B_ + b] = et;
}

// ---- CRF: gold score + forward algorithm + loss (256 threads, strided) ----
__global__ void k_crf(const int* __restrict__ y,
                      const float* __restrict__ start_t, const float* __restrict__ end_t,
                      const float* __restrict__ trans,
                      char* __restrict__ ws, float* __restrict__ out) {
  __shared__ float tr[81], st[TAGS], en[TAGS];
  __shared__ float alpha[2][B_][12];
  __shared__ float resS[B_], resD[B_];
  const float* em    = (const float*)(ws + EM_OFF);
  const float* emtag = (const float*)(ws + EMTAG_OFF);
  int tid = threadIdx.x;
  if (tid < 81) tr[tid] = trans[tid];
  if (tid < TAGS) { st[tid] = start_t[tid]; en[tid] = end_t[tid]; }
  __syncthreads();

  for (int it = tid; it < B_*TAGS; it += 256) {
    int b = it / TAGS, j = it % TAGS;
    alpha[0][b][j] = st[j] + em[(0*B_ + b)*TAGS + j];
  }

  if (tid < B_) {
    int b = tid;
    int y0 = y[b*S_]; bool m0 = (y0 != -1); int tg0 = m0 ? y0 : 0;
    float score = st[tg0] + emtag[0*B_ + b];
    int cnt = m0 ? 1 : 0;
    int prev = tg0;
    for (int t = 1; t < S_; ++t) {
      int yt = y[b*S_ + t]; bool mt = (yt != -1); int tg = mt ? yt : 0;
      float mf = mt ? 1.f : 0.f;
      score += (tr[prev*TAGS + tg] + emtag[t*B_ + b]) * mf;
      prev = tg;
      cnt += mt ? 1 : 0;
    }
    int li = cnt - 1; if (li < 0) li = 0;
    int yl = y[b*S_ + li]; int tgl = (yl != -1) ? yl : 0;
    score += en[tgl];
    resS[b] = score;
  }
  __syncthreads();

  for (int t = 1; t < S_; ++t) {
    int pb = (t-1) & 1, cb2 = t & 1;
    for (int it = tid; it < B_*TAGS; it += 256) {
      int b = it / TAGS, j = it % TAGS;
      float a[TAGS]; float m = -1e30f;
      #pragma unroll
      for (int i = 0; i < TAGS; ++i) { a[i] = alpha[pb][b][i] + tr[i*TAGS + j]; m = fmaxf(m, a[i]); }
      float ssum = 0.f;
      #pragma unroll
      for (int i = 0; i < TAGS; ++i) ssum += __expf(a[i] - m);
      float v = m + __logf(ssum) + em[((long)t*B_ + b)*TAGS + j];
      bool mt = (y[b*S_ + t] != -1);
      alpha[cb2][b][j] = mt ? v : alpha[pb][b][j];
    }
    __syncthreads();
  }

  int fb = (S_-1) & 1;
  if (tid < B_) {
    int b = tid;
    float a[TAGS]; float m = -1e30f;
    #pragma unroll
    for (int i = 0; i < TAGS; ++i) { a[i] = alpha[fb][b][i] + en[i]; m = fmaxf(m, a[i]); }
    float ssum = 0.f;
    #pragma unroll
    for (int i = 0; i < TAGS; ++i) ssum += __expf(a[i] - m);
    resD[b] = m + __logf(ssum);
  }
  __syncthreads();
  if (tid == 0) {
    float llh = 0.f;
    for (int bb = 0; bb < B_; ++bb) llh += resS[bb] - resD[bb];
    out[LOSS_IDX] = -llh;                          // FP32 loss at float element 73728
  }
}

extern "C" void kernel_launch(void* const* d_in, const int* in_sizes, int n_in,
                              void* d_out, int out_size, void* d_ws, size_t ws_size,
                              hipStream_t stream) {
  const int* x = (const int*)d_in[0];
  const int* y = (const int*)d_in[1];
  const float* emb   = (const float*)d_in[2];
  const float* wihf  = (const float*)d_in[3];
  const float* whhf  = (const float*)d_in[4];
  const float* bihf  = (const float*)d_in[5];
  const float* bhhf  = (const float*)d_in[6];
  const float* wihb  = (const float*)d_in[7];
  const float* whhb  = (const float*)d_in[8];
  const float* bihb  = (const float*)d_in[9];
  const float* bhhb  = (const float*)d_in[10];
  const float* lin_w = (const float*)d_in[11];
  const float* lin_b = (const float*)d_in[12];
  const float* sta   = (const float*)d_in[13];
  const float* endt  = (const float*)d_in[14];
  const float* trans = (const float*)d_in[15];
  char* ws = (char*)d_ws;
  float* out = (float*)d_out;                      // reference outputs are FP32

  const long n_init = 2L*2*B_*HP/4 + (long)S_*B_*TAGS + 2*(S_+1);
  int grid_init = (int)((n_init + 255) / 256);
  k_init<<<grid_init, 256, 0, stream>>>(lin_b, ws);
  k_lstm<<<2*NW, 256, 0, stream>>>(x, emb, wihf, whhf, bihf, bhhf,
                                   wihb, whhb, bihb, bhhb, lin_w, ws);
  k_emit<<<(B_*S_)/256, 256, 0, stream>>>(y, ws, out);
  k_crf<<<1, 256, 0, stream>>>(y, sta, endt, trans, ws, out);
}

// Round 15
// 2020.170 us; speedup vs baseline: 1.5356x; 1.5356x over previous
//
#include <hip/hip_runtime.h>
#include <hip/hip_bf16.h>

typedef __attribute__((ext_vector_type(8))) short s8v;
typedef __attribute__((ext_vector_type(4))) short s4v;
typedef __attribute__((ext_vector_type(4))) float f4v;

#define B_   32
#define S_   256
#define H_   300
#define HP   320
#define NW   19
#define TAGS 9

// workspace layout
#define HB_OFF    0                      // bf16 h ping-pong: 2dir*2slot*32*320*2 = 81920 B
#define LG_OFF    163840                 // fp32 logits acc: 256*32*9*4 = 294912 B
#define EM_OFF    458752                 // fp32 emissions: 256*32*9*4 = 294912 B
#define EMTAG_OFF 753664                 // fp32: 256*32*4 = 32768 B
#define ARR_OFF   786432                 // per-WG flags: 2*NW*16 ints (64B apart)

#define LOSS_IDX  ((long)B_*S_*TAGS)     // float element 73728

__device__ __forceinline__ short f2b(float f) {
  unsigned int u = __builtin_bit_cast(unsigned int, f);
  u = (u + 0x7FFFu + ((u >> 16) & 1u)) >> 16;      // RNE fp32 -> bf16
  return (short)u;
}
__device__ __forceinline__ float sigf(float x) { return 1.f / (1.f + __expf(-x)); }
__device__ __forceinline__ float tanh_f(float x) {
  x = fminf(fmaxf(x, -15.f), 15.f);
  float e = __expf(-2.f * x);
  return (1.f - e) / (1.f + e);
}

// ---- init: zero h ping-pong + per-WG flags, init logits accumulator with lin_b ----
__global__ void k_init(const float* __restrict__ lin_b, char* __restrict__ ws) {
  short* hb = (short*)(ws + HB_OFF);
  float* lg = (float*)(ws + LG_OFF);
  int* arr  = (int*)(ws + ARR_OFF);
  long u = (long)blockIdx.x * blockDim.x + threadIdx.x;
  const long N1 = 2L * 2 * B_ * HP / 4;            // s4v units of hb (10240)
  if (u < N1) {
    s4v z; z[0]=0; z[1]=0; z[2]=0; z[3]=0;
    *(s4v*)(hb + u * 4) = z;
    return;
  }
  u -= N1;
  const long N2 = (long)S_ * B_ * TAGS;            // lg init (73728)
  if (u < N2) {
    lg[u] = lin_b[(int)(u % TAGS)];
    return;
  }
  u -= N2;
  if (u < 2L*NW*16) arr[u] = 0;                    // per-WG flag words (padded)
}

// ---- persistent BiLSTM recurrence: ONE launch, 38 co-resident blocks ----
// handoff: packed agent-atomic h stores (no threadfence) + per-WG release-store
// flags on separate cachelines (no RMW serialization) + plain vector reads
// after acquire (cache-invalidating) spin.
__launch_bounds__(256, 1)
__global__ void k_lstm(const int* __restrict__ x, const float* __restrict__ emb,
                       const float* __restrict__ wihf, const float* __restrict__ whhf,
                       const float* __restrict__ bihf, const float* __restrict__ bhhf,
                       const float* __restrict__ wihb, const float* __restrict__ whhb,
                       const float* __restrict__ bihb, const float* __restrict__ bhhb,
                       const float* __restrict__ lin_w,
                       char* __restrict__ ws) {
  const int dir  = blockIdx.x / NW;
  const int wg   = blockIdx.x % NW;
  const int h0   = wg * 16;
  const int tid  = threadIdx.x;
  const int w    = tid >> 6;
  const int lane = tid & 63;
  const int mhat = w & 1;
  const int khalf= w >> 1;
  const int nl   = lane & 15;
  const int quad = lane >> 4;
  const int hg   = h0 + nl;                 // 0..303
  const bool hvalid = hg < H_;

  const float* Wih = dir ? wihb : wihf;
  const float* Whh = dir ? whhb : whhf;
  const float* Bih = dir ? bihb : bihf;
  const float* Bhh = dir ? bhhb : bhhf;

  short* hb = (short*)(ws + HB_OFF);
  float* lg = (float*)(ws + LG_OFF);
  int* arr  = (int*)(ws + ARR_OFF);         // flag word for (d,w) at [(d*NW+w)*16]

  __shared__ int   sh_idx[32];
  __shared__ short sh_x[B_*328];
  __shared__ short sh_h[B_*328];
  __shared__ float red[2*4*64*4];
  __shared__ float shl[B_*17];              // fp32 h of this WG's 16 dims
  __shared__ float lwl[TAGS*16];            // lin_w tile for this WG

  // ---- one-time: build weight B-fragments from fp32 into registers ----
  s8v wf[2][4][5];
  #pragma unroll
  for (int mat = 0; mat < 2; ++mat) {
    const float* W = mat ? Whh : Wih;
    #pragma unroll
    for (int nt = 0; nt < 4; ++nt) {
      const long rowbase = (long)(nt * H_ + hg) * H_;
      #pragma unroll
      for (int kci = 0; kci < 5; ++kci) {
        int kb = (khalf*5 + kci)*32 + quad*8;
        s8v v; v[0]=0;v[1]=0;v[2]=0;v[3]=0;v[4]=0;v[5]=0;v[6]=0;v[7]=0;
        if (hvalid) {
          #pragma unroll
          for (int half = 0; half < 2; ++half) {
            int k0 = kb + half*4;
            if (k0 + 4 <= H_) {
              f4v q = *(const f4v*)(W + rowbase + k0);    // 16B aligned
              v[half*4+0] = f2b(q[0]);
              v[half*4+1] = f2b(q[1]);
              v[half*4+2] = f2b(q[2]);
              v[half*4+3] = f2b(q[3]);
            } else {
              #pragma unroll
              for (int j = 0; j < 4; ++j) {
                int k = k0 + j;
                if (k < H_) v[half*4+j] = f2b(W[rowbase + k]);
              }
            }
          }
        }
        wf[mat][nt][kci] = v;
      }
    }
  }

  float bias[4];
  #pragma unroll
  for (int nt = 0; nt < 4; ++nt)
    bias[nt] = hvalid ? (Bih[nt*H_ + hg] + Bhh[nt*H_ + hg]) : 0.f;

  if (tid < TAGS*16) {
    int tg = tid / 16, n = tid % 16, hh = h0 + n;
    lwl[tid] = (hh < H_) ? lin_w[tg*(2*H_) + dir*H_ + hh] : 0.f;
  }

  float creg[4] = {0.f, 0.f, 0.f, 0.f};     // c-state lives in registers
  const int arow = (mhat*16 + nl) * 328 + quad * 8;

  for (int s = 0; s < S_; ++s) {
    const int t = dir ? (S_ - 1 - s) : s;

    if (tid < 32) sh_idx[tid] = x[tid*S_ + t];
    __syncthreads();                               // sh_idx ready; prev-iter LDS retired

    // stage x(t): fp32 emb rows -> bf16 LDS (zero-pad K to 320) — before the wait
    #pragma unroll
    for (int i = 0; i < 5; ++i) {
      int u = tid + i*256;
      int b = u / 40, kg = u % 40;
      int k0 = kg * 8;
      const float* rp = emb + (long)sh_idx[b] * H_;
      s8v v; v[0]=0;v[1]=0;v[2]=0;v[3]=0;v[4]=0;v[5]=0;v[6]=0;v[7]=0;
      if (k0 + 8 <= H_) {
        f4v a = *(const f4v*)(rp + k0);
        f4v c = *(const f4v*)(rp + k0 + 4);
        v[0]=f2b(a[0]); v[1]=f2b(a[1]); v[2]=f2b(a[2]); v[3]=f2b(a[3]);
        v[4]=f2b(c[0]); v[5]=f2b(c[1]); v[6]=f2b(c[2]); v[7]=f2b(c[3]);
      } else if (k0 < H_) {
        f4v a = *(const f4v*)(rp + k0);            // k0=296: loads 296..299
        v[0]=f2b(a[0]); v[1]=f2b(a[1]); v[2]=f2b(a[2]); v[3]=f2b(a[3]);
      }
      *(s8v*)&sh_x[b*328 + k0] = v;
    }
    __syncthreads();                               // sync1: sh_x ready

    f4v acc[4];
    #pragma unroll
    for (int nt = 0; nt < 4; ++nt) { acc[nt][0]=0.f; acc[nt][1]=0.f; acc[nt][2]=0.f; acc[nt][3]=0.f; }

    // x-GEMM first: overlaps with waiting for peers' h(s)
    #pragma unroll
    for (int kci = 0; kci < 5; ++kci) {
      s8v a = *(const s8v*)&sh_x[arow + (khalf*5 + kci)*32];
      #pragma unroll
      for (int nt = 0; nt < 4; ++nt)
        acc[nt] = __builtin_amdgcn_mfma_f32_16x16x32_bf16(a, wf[0][nt][kci], acc[nt], 0, 0, 0);
    }

    // wait: 19 parallel acquire spins on independent cachelines (no RMW)
    if (s > 0 && tid < NW) {
      const int* fl = &arr[(dir*NW + tid)*16];
      while (__hip_atomic_load(fl, __ATOMIC_ACQUIRE, __HIP_MEMORY_SCOPE_AGENT) < s)
        __builtin_amdgcn_s_sleep(1);
    }
    __syncthreads();                               // sync2

    // stage h(s) from ping-pong slot s&1 (plain vector loads, post-acquire)
    {
      const short* hsrc = hb + (long)(dir*2 + (s & 1)) * B_ * HP;
      #pragma unroll
      for (int i = 0; i < 5; ++i) {
        int u = tid + i*256;
        int b = u / 40, kg = u % 40;
        *(s8v*)&sh_h[b*328 + kg*8] = *(const s8v*)&hsrc[b*HP + kg*8];
      }
    }
    __syncthreads();                               // sync3

    #pragma unroll
    for (int kci = 0; kci < 5; ++kci) {
      s8v a = *(const s8v*)&sh_h[arow + (khalf*5 + kci)*32];
      #pragma unroll
      for (int nt = 0; nt < 4; ++nt)
        acc[nt] = __builtin_amdgcn_mfma_f32_16x16x32_bf16(a, wf[1][nt][kci], acc[nt], 0, 0, 0);
    }

    // K-half reduction
    if (khalf == 1) {
      #pragma unroll
      for (int nt = 0; nt < 4; ++nt)
        *(f4v*)&red[((mhat*4 + nt)*64 + lane)*4] = acc[nt];
    }
    __syncthreads();                               // sync4

    if (khalf == 0) {
      #pragma unroll
      for (int nt = 0; nt < 4; ++nt) {
        f4v o = *(const f4v*)&red[((mhat*4 + nt)*64 + lane)*4];
        acc[nt][0]+=o[0]; acc[nt][1]+=o[1]; acc[nt][2]+=o[2]; acc[nt][3]+=o[3];
      }
      #pragma unroll
      for (int r = 0; r < 4; ++r) {
        int b = mhat*16 + quad*4 + r;
        float gi = acc[0][r] + bias[0];
        float gf = acc[1][r] + bias[1];
        float gg = acc[2][r] + bias[2];
        float go = acc[3][r] + bias[3];
        float c  = sigf(gf) * creg[r] + sigf(gi) * tanh_f(gg);
        float h  = sigf(go) * tanh_f(c);
        creg[r] = c;
        shl[b*17 + nl] = h;                        // LDS only; publish below
      }
    }
    __syncthreads();                               // sync5: shl ready

    // publish h(s+1): pack 2 bf16/dword, agent-scope atomic stores (all 256 thr)
    {
      int b = tid >> 3, j = tid & 7;               // 32 rows x 8 dword-cols
      float fa = shl[b*17 + 2*j];
      float fb = shl[b*17 + 2*j + 1];
      unsigned int pack = (unsigned int)(unsigned short)f2b(fa) |
                          ((unsigned int)(unsigned short)f2b(fb) << 16);
      unsigned int* dsti = (unsigned int*)(hb + (long)(dir*2 + ((s+1) & 1)) * B_ * HP);
      __hip_atomic_store(&dsti[b*160 + (h0 >> 1) + j], pack,
                         __ATOMIC_RELAXED, __HIP_MEMORY_SCOPE_AGENT);
    }
    __syncthreads();                               // sync6: vmcnt drained -> stores visible
    if (s + 1 < S_ && tid == 0)
      __hip_atomic_store(&arr[(dir*NW + wg)*16], s + 1,
                         __ATOMIC_RELEASE, __HIP_MEMORY_SCOPE_AGENT);

    // logits partial for position t (off critical path, after release)
    if (tid < B_*TAGS) {
      int b = tid / TAGS, tg = tid % TAGS;
      float sum = 0.f;
      #pragma unroll
      for (int n = 0; n < 16; ++n) sum += shl[b*17 + n] * lwl[tg*16 + n];
      atomicAdd(&lg[((long)t*B_ + b)*TAGS + tg], sum);
    }
  }
}

// ---- emit: softmax(lg) -> probs (out, FP32) + emissions/emtag (ws, fp32) ----
__global__ void k_emit(const int* __restrict__ y, char* __restrict__ ws,
                       float* __restrict__ out) {
  const float* lg = (const float*)(ws + LG_OFF);
  float* em    = (float*)(ws + EM_OFF);
  float* emtag = (float*)(ws + EMTAG_OFF);
  int g = blockIdx.x * blockDim.x + threadIdx.x;   // 8192
  int b = g & 31, t = g >> 5;

  float l[TAGS];
  #pragma unroll
  for (int tg = 0; tg < TAGS; ++tg) l[tg] = lg[((long)t*B_ + b)*TAGS + tg];
  float m = l[0];
  #pragma unroll
  for (int tg = 1; tg < TAGS; ++tg) m = fmaxf(m, l[tg]);
  float p[TAGS]; float sum = 0.f;
  #pragma unroll
  for (int tg = 0; tg < TAGS; ++tg) { p[tg] = __expf(l[tg] - m); sum += p[tg]; }
  float inv = 1.f / sum;

  int yy = y[b*S_ + t];
  int sel = (yy != -1) ? yy : 0;
  float et = 0.f;
  #pragma unroll
  for (int tg = 0; tg < TAGS; ++tg) {
    float pv = p[tg] * inv;
    out[((long)b*S_ + t)*TAGS + tg] = pv;          // FP32 output
    em[((long)t*B_ + b)*TAGS + tg] = pv;
    if (tg == sel) et = pv;
  }
  emtag[t*B_ + b] = et;
}

// ---- CRF: gold score + forward algorithm + loss (256 threads, strided) ----
__global__ void k_crf(const int* __restrict__ y,
                      const float* __restrict__ start_t, const float* __restrict__ end_t,
                      const float* __restrict__ trans,
                      char* __restrict__ ws, float* __restrict__ out) {
  __shared__ float tr[81], st[TAGS], en[TAGS];
  __shared__ float alpha[2][B_][12];
  __shared__ float resS[B_], resD[B_];
  const float* em    = (const float*)(ws + EM_OFF);
  const float* emtag = (const float*)(ws + EMTAG_OFF);
  int tid = threadIdx.x;
  if (tid < 81) tr[tid] = trans[tid];
  if (tid < TAGS) { st[tid] = start_t[tid]; en[tid] = end_t[tid]; }
  __syncthreads();

  for (int it = tid; it < B_*TAGS; it += 256) {
    int b = it / TAGS, j = it % TAGS;
    alpha[0][b][j] = st[j] + em[(0*B_ + b)*TAGS + j];
  }

  if (tid < B_) {
    int b = tid;
    int y0 = y[b*S_]; bool m0 = (y0 != -1); int tg0 = m0 ? y0 : 0;
    float score = st[tg0] + emtag[0*B_ + b];
    int cnt = m0 ? 1 : 0;
    int prev = tg0;
    for (int t = 1; t < S_; ++t) {
      int yt = y[b*S_ + t]; bool mt = (yt != -1); int tg = mt ? yt : 0;
      float mf = mt ? 1.f : 0.f;
      score += (tr[prev*TAGS + tg] + emtag[t*B_ + b]) * mf;
      prev = tg;
      cnt += mt ? 1 : 0;
    }
    int li = cnt - 1; if (li < 0) li = 0;
    int yl = y[b*S_ + li]; int tgl = (yl != -1) ? yl : 0;
    score += en[tgl];
    resS[b] = score;
  }
  __syncthreads();

  for (int t = 1; t < S_; ++t) {
    int pb = (t-1) & 1, cb2 = t & 1;
    for (int it = tid; it < B_*TAGS; it += 256) {
      int b = it / TAGS, j = it % TAGS;
      float a[TAGS]; float m = -1e30f;
      #pragma unroll
      for (int i = 0; i < TAGS; ++i) { a[i] = alpha[pb][b][i] + tr[i*TAGS + j]; m = fmaxf(m, a[i]); }
      float ssum = 0.f;
      #pragma unroll
      for (int i = 0; i < TAGS; ++i) ssum += __expf(a[i] - m);
      float v = m + __logf(ssum) + em[((long)t*B_ + b)*TAGS + j];
      bool mt = (y[b*S_ + t] != -1);
      alpha[cb2][b][j] = mt ? v : alpha[pb][b][j];
    }
    __syncthreads();
  }

  int fb = (S_-1) & 1;
  if (tid < B_) {
    int b = tid;
    float a[TAGS]; float m = -1e30f;
    #pragma unroll
    for (int i = 0; i < TAGS; ++i) { a[i] = alpha[fb][b][i] + en[i]; m = fmaxf(m, a[i]); }
    float ssum = 0.f;
    #pragma unroll
    for (int i = 0; i < TAGS; ++i) ssum += __expf(a[i] - m);
    resD[b] = m + __logf(ssum);
  }
  __syncthreads();
  if (tid == 0) {
    float llh = 0.f;
    for (int bb = 0; bb < B_; ++bb) llh += resS[bb] - resD[bb];
    out[LOSS_IDX] = -llh;                          // FP32 loss at float element 73728
  }
}

extern "C" void kernel_launch(void* const* d_in, const int* in_sizes, int n_in,
                              void* d_out, int out_size, void* d_ws, size_t ws_size,
                              hipStream_t stream) {
  const int* x = (const int*)d_in[0];
  const int* y = (const int*)d_in[1];
  const float* emb   = (const float*)d_in[2];
  const float* wihf  = (const float*)d_in[3];
  const float* whhf  = (const float*)d_in[4];
  const float* bihf  = (const float*)d_in[5];
  const float* bhhf  = (const float*)d_in[6];
  const float* wihb  = (const float*)d_in[7];
  const float* whhb  = (const float*)d_in[8];
  const float* bihb  = (const float*)d_in[9];
  const float* bhhb  = (const float*)d_in[10];
  const float* lin_w = (const float*)d_in[11];
  const float* lin_b = (const float*)d_in[12];
  const float* sta   = (const float*)d_in[13];
  const float* endt  = (const float*)d_in[14];
  const float* trans = (const float*)d_in[15];
  char* ws = (char*)d_ws;
  float* out = (float*)d_out;                      // reference outputs are FP32

  const long n_init = 2L*2*B_*HP/4 + (long)S_*B_*TAGS + 2L*NW*16;
  int grid_init = (int)((n_init + 255) / 256);
  k_init<<<grid_init, 256, 0, stream>>>(lin_b, ws);
  k_lstm<<<2*NW, 256, 0, stream>>>(x, emb, wihf, whhf, bihf, bhhf,
                                   wihb, whhb, bihb, bhhb, lin_w, ws);
  k_emit<<<(B_*S_)/256, 256, 0, stream>>>(y, ws, out);
  k_crf<<<1, 256, 0, stream>>>(y, sta, endt, trans, ws, out);
}

// Round 16
// 1495.310 us; speedup vs baseline: 2.0746x; 1.3510x over previous
//
#include <hip/hip_runtime.h>
#include <hip/hip_bf16.h>

typedef __attribute__((ext_vector_type(8))) short s8v;
typedef __attribute__((ext_vector_type(4))) short s4v;
typedef __attribute__((ext_vector_type(4))) float f4v;

#define B_   32
#define S_   256
#define H_   300
#define HP   320
#define NW   19
#define TAGS 9

// workspace layout (~14.9 MB; r0 proved >=16.3 MB writable)
#define XS_OFF    0                      // bf16 staged embeddings: 256*32*320*2 = 5242880 B
#define HB_OFF    5242880                // bf16 h ping-pong: 2dir*2slot*32*320*2 = 81920 B
#define HIST_OFF  5324800                // bf16 h history: 256*32*608*2 = 9961472 B
#define EM_OFF    15286272               // fp32 emissions: 256*32*9*4 = 294912 B
#define EMTAG_OFF 15581184               // fp32: 256*32*4 = 32768 B
#define ARR_OFF   15613952               // per-WG flags: 2*NW*16 ints (64B apart)

#define LOSS_IDX  ((long)B_*S_*TAGS)     // float element 73728

__device__ __forceinline__ short f2b(float f) {
  unsigned int u = __builtin_bit_cast(unsigned int, f);
  u = (u + 0x7FFFu + ((u >> 16) & 1u)) >> 16;      // RNE fp32 -> bf16
  return (short)u;
}
__device__ __forceinline__ float b2f(unsigned int lo16) {
  return __builtin_bit_cast(float, lo16 << 16);
}
__device__ __forceinline__ float sigf(float x) { return 1.f / (1.f + __expf(-x)); }
__device__ __forceinline__ float tanh_f(float x) {
  x = fminf(fmaxf(x, -15.f), 15.f);
  float e = __expf(-2.f * x);
  return (1.f - e) / (1.f + e);
}

// ---- init: gather emb->bf16 xs (padded K 320), zero h ping-pong + flags ----
__global__ void k_init(const int* __restrict__ x, const float* __restrict__ emb,
                       char* __restrict__ ws) {
  short* xs = (short*)(ws + XS_OFF);
  short* hb = (short*)(ws + HB_OFF);
  int* arr  = (int*)(ws + ARR_OFF);
  long u = (long)blockIdx.x * blockDim.x + threadIdx.x;
  const long N1 = (long)S_ * B_ * 80;              // s4v units of xs
  if (u < N1) {
    int kg = (int)(u % 80);
    long tb = u / 80;
    int b = (int)(tb % B_);
    int t = (int)(tb / B_);
    int k = kg * 4;
    s4v v; v[0]=0; v[1]=0; v[2]=0; v[3]=0;
    if (k + 4 <= H_) {                             // emb rows are 16B aligned (300%4==0)
      int row = x[b * S_ + t];
      f4v q = *(const f4v*)(emb + (long)row * H_ + k);
      v[0]=f2b(q[0]); v[1]=f2b(q[1]); v[2]=f2b(q[2]); v[3]=f2b(q[3]);
    }
    *(s4v*)(xs + ((long)t * B_ + b) * HP + k) = v;
    return;
  }
  u -= N1;
  const long N2 = 2L * 2 * B_ * HP / 4;            // s4v units of hb
  if (u < N2) {
    s4v z; z[0]=0; z[1]=0; z[2]=0; z[3]=0;
    *(s4v*)(hb + u * 4) = z;
    return;
  }
  u -= N2;
  if (u < 2L*NW*16) arr[u] = 0;
}

// ---- persistent BiLSTM recurrence: ONE launch, 38 co-resident blocks ----
__launch_bounds__(256, 1)
__global__ void k_lstm(const float* __restrict__ wihf, const float* __restrict__ whhf,
                       const float* __restrict__ bihf, const float* __restrict__ bhhf,
                       const float* __restrict__ wihb, const float* __restrict__ whhb,
                       const float* __restrict__ bihb, const float* __restrict__ bhhb,
                       char* __restrict__ ws) {
  const int dir  = blockIdx.x / NW;
  const int wg   = blockIdx.x % NW;
  const int h0   = wg * 16;
  const int tid  = threadIdx.x;
  const int w    = tid >> 6;
  const int lane = tid & 63;
  const int mhat = w & 1;
  const int khalf= w >> 1;
  const int nl   = lane & 15;
  const int quad = lane >> 4;
  const int hg   = h0 + nl;                 // 0..303
  const bool hvalid = hg < H_;

  const float* Wih = dir ? wihb : wihf;
  const float* Whh = dir ? whhb : whhf;
  const float* Bih = dir ? bihb : bihf;
  const float* Bhh = dir ? bhhb : bhhf;

  const short* xs = (const short*)(ws + XS_OFF);
  short* hb = (short*)(ws + HB_OFF);
  unsigned int* hist = (unsigned int*)(ws + HIST_OFF);   // 304 dwords per (t,b) row
  int* arr  = (int*)(ws + ARR_OFF);

  __shared__ short sh_x[B_*328];
  __shared__ short sh_h[B_*328];
  __shared__ float red[2*4*64*4];
  __shared__ float shl[B_*17];              // fp32 h of this WG's 16 dims

  // ---- one-time: build weight B-fragments from fp32 into registers ----
  s8v wf[2][4][5];
  #pragma unroll
  for (int mat = 0; mat < 2; ++mat) {
    const float* W = mat ? Whh : Wih;
    #pragma unroll
    for (int nt = 0; nt < 4; ++nt) {
      const long rowbase = (long)(nt * H_ + hg) * H_;
      #pragma unroll
      for (int kci = 0; kci < 5; ++kci) {
        int kb = (khalf*5 + kci)*32 + quad*8;
        s8v v; v[0]=0;v[1]=0;v[2]=0;v[3]=0;v[4]=0;v[5]=0;v[6]=0;v[7]=0;
        if (hvalid) {
          #pragma unroll
          for (int half = 0; half < 2; ++half) {
            int k0 = kb + half*4;
            if (k0 + 4 <= H_) {
              f4v q = *(const f4v*)(W + rowbase + k0);    // 16B aligned
              v[half*4+0] = f2b(q[0]);
              v[half*4+1] = f2b(q[1]);
              v[half*4+2] = f2b(q[2]);
              v[half*4+3] = f2b(q[3]);
            } else {
              #pragma unroll
              for (int j = 0; j < 4; ++j) {
                int k = k0 + j;
                if (k < H_) v[half*4+j] = f2b(W[rowbase + k]);
              }
            }
          }
        }
        wf[mat][nt][kci] = v;
      }
    }
  }

  float bias[4];
  #pragma unroll
  for (int nt = 0; nt < 4; ++nt)
    bias[nt] = hvalid ? (Bih[nt*H_ + hg] + Bhh[nt*H_ + hg]) : 0.f;

  float creg[4] = {0.f, 0.f, 0.f, 0.f};     // c-state lives in registers
  const int arow = (mhat*16 + nl) * 328 + quad * 8;

  for (int s = 0; s < S_; ++s) {
    const int t = dir ? (S_ - 1 - s) : s;

    // stage x(t) from precomputed bf16 xs (coalesced; LLC-resident)
    {
      const short* xsrc = xs + (long)t * B_ * HP;
      #pragma unroll
      for (int i = 0; i < 5; ++i) {
        int u = tid + i*256;
        int b = u / 40, kg = u % 40;
        *(s8v*)&sh_x[b*328 + kg*8] = *(const s8v*)&xsrc[b*HP + kg*8];
      }
    }
    __syncthreads();                               // sync1: sh_x ready

    f4v acc[4];
    #pragma unroll
    for (int nt = 0; nt < 4; ++nt) { acc[nt][0]=0.f; acc[nt][1]=0.f; acc[nt][2]=0.f; acc[nt][3]=0.f; }

    // x-GEMM first: overlaps with peers finishing step s-1
    #pragma unroll
    for (int kci = 0; kci < 5; ++kci) {
      s8v a = *(const s8v*)&sh_x[arow + (khalf*5 + kci)*32];
      #pragma unroll
      for (int nt = 0; nt < 4; ++nt)
        acc[nt] = __builtin_amdgcn_mfma_f32_16x16x32_bf16(a, wf[0][nt][kci], acc[nt], 0, 0, 0);
    }

    // wait: 19 parallel acquire spins on independent cachelines (tight, no sleep)
    if (s > 0 && tid < NW) {
      const int* fl = &arr[(dir*NW + tid)*16];
      while (__hip_atomic_load(fl, __ATOMIC_ACQUIRE, __HIP_MEMORY_SCOPE_AGENT) < s) { }
    }
    __syncthreads();                               // sync2

    // stage h(s) from ping-pong slot s&1 (plain vector loads, post-acquire)
    {
      const short* hsrc = hb + (long)(dir*2 + (s & 1)) * B_ * HP;
      #pragma unroll
      for (int i = 0; i < 5; ++i) {
        int u = tid + i*256;
        int b = u / 40, kg = u % 40;
        *(s8v*)&sh_h[b*328 + kg*8] = *(const s8v*)&hsrc[b*HP + kg*8];
      }
    }
    __syncthreads();                               // sync3

    #pragma unroll
    for (int kci = 0; kci < 5; ++kci) {
      s8v a = *(const s8v*)&sh_h[arow + (khalf*5 + kci)*32];
      #pragma unroll
      for (int nt = 0; nt < 4; ++nt)
        acc[nt] = __builtin_amdgcn_mfma_f32_16x16x32_bf16(a, wf[1][nt][kci], acc[nt], 0, 0, 0);
    }

    // K-half reduction
    if (khalf == 1) {
      #pragma unroll
      for (int nt = 0; nt < 4; ++nt)
        *(f4v*)&red[((mhat*4 + nt)*64 + lane)*4] = acc[nt];
    }
    __syncthreads();                               // sync4

    if (khalf == 0) {
      #pragma unroll
      for (int nt = 0; nt < 4; ++nt) {
        f4v o = *(const f4v*)&red[((mhat*4 + nt)*64 + lane)*4];
        acc[nt][0]+=o[0]; acc[nt][1]+=o[1]; acc[nt][2]+=o[2]; acc[nt][3]+=o[3];
      }
      #pragma unroll
      for (int r = 0; r < 4; ++r) {
        int b = mhat*16 + quad*4 + r;
        float gi = acc[0][r] + bias[0];
        float gf = acc[1][r] + bias[1];
        float gg = acc[2][r] + bias[2];
        float go = acc[3][r] + bias[3];
        float c  = sigf(gf) * creg[r] + sigf(gi) * tanh_f(gg);
        float h  = sigf(go) * tanh_f(c);
        creg[r] = c;
        shl[b*17 + nl] = h;                        // LDS only; publish below
      }
    }
    __syncthreads();                               // sync5: shl ready

    // publish h(s+1) (agent-atomic dwords) + history (plain dwords)
    {
      int b = tid >> 3, j = tid & 7;               // 32 rows x 8 dword-cols
      float fa = shl[b*17 + 2*j];
      float fb = shl[b*17 + 2*j + 1];
      unsigned int pack = (unsigned int)(unsigned short)f2b(fa) |
                          ((unsigned int)(unsigned short)f2b(fb) << 16);
      unsigned int* dsti = (unsigned int*)(hb + (long)(dir*2 + ((s+1) & 1)) * B_ * HP);
      __hip_atomic_store(&dsti[b*160 + (h0 >> 1) + j], pack,
                         __ATOMIC_RELAXED, __HIP_MEMORY_SCOPE_AGENT);
      hist[((long)t * B_ + b) * 304 + dir*152 + (h0 >> 1) + j] = pack;
    }
    __syncthreads();                               // sync6: vmcnt drained -> stores visible
    if (s + 1 < S_ && tid == 0)
      __hip_atomic_store(&arr[(dir*NW + wg)*16], s + 1,
                         __ATOMIC_RELEASE, __HIP_MEMORY_SCOPE_AGENT);
  }
}

// ---- logits + softmax + emit from h history ----
__global__ void k_logits(const int* __restrict__ y,
                         const float* __restrict__ lin_w, const float* __restrict__ lin_b,
                         char* __restrict__ ws, float* __restrict__ out) {
  __shared__ float lw[600*10];                     // lw[j*10+tg] = lin_w[tg][j], broadcast-friendly
  const unsigned int* hist = (const unsigned int*)(ws + HIST_OFF);
  float* em    = (float*)(ws + EM_OFF);
  float* emtag = (float*)(ws + EMTAG_OFF);
  int tid = threadIdx.x;
  for (int i = tid; i < 600*TAGS; i += 256) {
    int j = i / TAGS, tg = i % TAGS;
    lw[j*10 + tg] = lin_w[tg*600 + j];
  }
  __syncthreads();

  int g = blockIdx.x * 256 + tid;                  // 8192
  int b = g & 31, t = g >> 5;
  const unsigned int* hrow = hist + ((long)t * B_ + b) * 304;

  float lg[TAGS];
  #pragma unroll
  for (int tg = 0; tg < TAGS; ++tg) lg[tg] = lin_b[tg];

  for (int jd = 0; jd < 150; ++jd) {               // dir0: cols 0..299
    unsigned int v = hrow[jd];
    float ha = b2f(v & 0xffffu), hc = b2f(v >> 16);
    int j0 = 2*jd;
    #pragma unroll
    for (int tg = 0; tg < TAGS; ++tg)
      lg[tg] += ha * lw[j0*10 + tg] + hc * lw[(j0+1)*10 + tg];
  }
  for (int jd = 0; jd < 150; ++jd) {               // dir1: cols 300..599
    unsigned int v = hrow[152 + jd];
    float ha = b2f(v & 0xffffu), hc = b2f(v >> 16);
    int j0 = 300 + 2*jd;
    #pragma unroll
    for (int tg = 0; tg < TAGS; ++tg)
      lg[tg] += ha * lw[j0*10 + tg] + hc * lw[(j0+1)*10 + tg];
  }

  float m = lg[0];
  #pragma unroll
  for (int tg = 1; tg < TAGS; ++tg) m = fmaxf(m, lg[tg]);
  float p[TAGS]; float sum = 0.f;
  #pragma unroll
  for (int tg = 0; tg < TAGS; ++tg) { p[tg] = __expf(lg[tg] - m); sum += p[tg]; }
  float inv = 1.f / sum;

  int yy = y[b*S_ + t];
  int sel = (yy != -1) ? yy : 0;
  float et = 0.f;
  #pragma unroll
  for (int tg = 0; tg < TAGS; ++tg) {
    float pv = p[tg] * inv;
    out[((long)b*S_ + t)*TAGS + tg] = pv;          // FP32 output
    em[((long)t*B_ + b)*TAGS + tg] = pv;
    if (tg == sel) et = pv;
  }
  emtag[t*B_ + b] = et;
}

// ---- CRF: gold score + forward algorithm + loss (256 threads, strided) ----
__global__ void k_crf(const int* __restrict__ y,
                      const float* __restrict__ start_t, const float* __restrict__ end_t,
                      const float* __restrict__ trans,
                      char* __restrict__ ws, float* __restrict__ out) {
  __shared__ float tr[81], st[TAGS], en[TAGS];
  __shared__ float alpha[2][B_][12];
  __shared__ float resS[B_], resD[B_];
  const float* em    = (const float*)(ws + EM_OFF);
  const float* emtag = (const float*)(ws + EMTAG_OFF);
  int tid = threadIdx.x;
  if (tid < 81) tr[tid] = trans[tid];
  if (tid < TAGS) { st[tid] = start_t[tid]; en[tid] = end_t[tid]; }
  __syncthreads();

  for (int it = tid; it < B_*TAGS; it += 256) {
    int b = it / TAGS, j = it % TAGS;
    alpha[0][b][j] = st[j] + em[(0*B_ + b)*TAGS + j];
  }

  if (tid < B_) {
    int b = tid;
    int y0 = y[b*S_]; bool m0 = (y0 != -1); int tg0 = m0 ? y0 : 0;
    float score = st[tg0] + emtag[0*B_ + b];
    int cnt = m0 ? 1 : 0;
    int prev = tg0;
    for (int t = 1; t < S_; ++t) {
      int yt = y[b*S_ + t]; bool mt = (yt != -1); int tg = mt ? yt : 0;
      float mf = mt ? 1.f : 0.f;
      score += (tr[prev*TAGS + tg] + emtag[t*B_ + b]) * mf;
      prev = tg;
      cnt += mt ? 1 : 0;
    }
    int li = cnt - 1; if (li < 0) li = 0;
    int yl = y[b*S_ + li]; int tgl = (yl != -1) ? yl : 0;
    score += en[tgl];
    resS[b] = score;
  }
  __syncthreads();

  for (int t = 1; t < S_; ++t) {
    int pb = (t-1) & 1, cb2 = t & 1;
    for (int it = tid; it < B_*TAGS; it += 256) {
      int b = it / TAGS, j = it % TAGS;
      float a[TAGS]; float m = -1e30f;
      #pragma unroll
      for (int i = 0; i < TAGS; ++i) { a[i] = alpha[pb][b][i] + tr[i*TAGS + j]; m = fmaxf(m, a[i]); }
      float ssum = 0.f;
      #pragma unroll
      for (int i = 0; i < TAGS; ++i) ssum += __expf(a[i] - m);
      float v = m + __logf(ssum) + em[((long)t*B_ + b)*TAGS + j];
      bool mt = (y[b*S_ + t] != -1);
      alpha[cb2][b][j] = mt ? v : alpha[pb][b][j];
    }
    __syncthreads();
  }

  int fb = (S_-1) & 1;
  if (tid < B_) {
    int b = tid;
    float a[TAGS]; float m = -1e30f;
    #pragma unroll
    for (int i = 0; i < TAGS; ++i) { a[i] = alpha[fb][b][i] + en[i]; m = fmaxf(m, a[i]); }
    float ssum = 0.f;
    #pragma unroll
    for (int i = 0; i < TAGS; ++i) ssum += __expf(a[i] - m);
    resD[b] = m + __logf(ssum);
  }
  __syncthreads();
  if (tid == 0) {
    float llh = 0.f;
    for (int bb = 0; bb < B_; ++bb) llh += resS[bb] - resD[bb];
    out[LOSS_IDX] = -llh;                          // FP32 loss at float element 73728
  }
}

extern "C" void kernel_launch(void* const* d_in, const int* in_sizes, int n_in,
                              void* d_out, int out_size, void* d_ws, size_t ws_size,
                              hipStream_t stream) {
  const int* x = (const int*)d_in[0];
  const int* y = (const int*)d_in[1];
  const float* emb   = (const float*)d_in[2];
  const float* wihf  = (const float*)d_in[3];
  const float* whhf  = (const float*)d_in[4];
  const float* bihf  = (const float*)d_in[5];
  const float* bhhf  = (const float*)d_in[6];
  const float* wihb  = (const float*)d_in[7];
  const float* whhb  = (const float*)d_in[8];
  const float* bihb  = (const float*)d_in[9];
  const float* bhhb  = (const float*)d_in[10];
  const float* lin_w = (const float*)d_in[11];
  const float* lin_b = (const float*)d_in[12];
  const float* sta   = (const float*)d_in[13];
  const float* endt  = (const float*)d_in[14];
  const float* trans = (const float*)d_in[15];
  char* ws = (char*)d_ws;
  float* out = (float*)d_out;                      // reference outputs are FP32

  const long n_init = (long)S_*B_*80 + 2L*2*B_*HP/4 + 2L*NW*16;
  int grid_init = (int)((n_init + 255) / 256);
  k_init<<<grid_init, 256, 0, stream>>>(x, emb, ws);
  k_lstm<<<2*NW, 256, 0, stream>>>(wihf, whhf, bihf, bhhf,
                                   wihb, whhb, bihb, bhhb, ws);
  k_logits<<<(B_*S_)/256, 256, 0, stream>>>(y, lin_w, lin_b, ws, out);
  k_crf<<<1, 256, 0, stream>>>(y, sta, endt, trans, ws, out);
}